// Round 10
// baseline (207.718 us; speedup 1.0000x reference)
//
#include <hip/hip_runtime.h>
#include <stdint.h>

// u   = 0.01 * (x @ x2h)   [B=524288, K=32, N=256]
// spk = zeros              [B, 256]
// h2h is dead (recurrent state is zero for the single time step).
//
// R4/R9 kernel (proven 205us; iteration body FROZEN — R7/R8 showed any
// reorder of [wait][compute+NT-store][prefetch] amplifies HBM traffic ~10x).
// Single delta vs R9: grid 4096 -> 2048 blocks (nch 8 -> 16). 2048 blocks
// x 8 blocks/CU = exactly one resident generation (4096 needed two), so the
// mid-kernel generation handoff and the duplicated prologue (2 cold stage
// loads per wave) are halved in aggregate.

#define NHID 256
#define NINP 32
#define RPC  8          // rows per chunk: 8*128B = 1 KB = one global_load_lds_dwordx4/wave

typedef float __attribute__((ext_vector_type(4))) f32x4;
typedef float __attribute__((ext_vector_type(2))) f32x2;

__device__ __forceinline__ void stage_chunk(const float* src_lane, void* lds_wave_base) {
    // global src is per-lane; LDS dst is wave-uniform base + lane*16 (HW rule).
    __builtin_amdgcn_global_load_lds(
        (const __attribute__((address_space(1))) uint32_t*)src_lane,
        (__attribute__((address_space(3))) uint32_t*)lds_wave_base,
        16, 0, 0);
}

__global__ __launch_bounds__(256, 4) void lsm_kernel(
    const float* __restrict__ x, const float* __restrict__ x2h,
    float* __restrict__ u, float* __restrict__ spk,
    int B, int nwaves)
{
    __shared__ float xbuf[4][2][RPC * NINP];   // 4 waves x double-buffer x 1 KB = 8 KB

    const int lane = threadIdx.x & 63;
    const int wv   = threadIdx.x >> 6;
    const int wid  = __builtin_amdgcn_readfirstlane(blockIdx.x * 4 + wv);

    // Wave pair: even wave = cols [0,128), odd wave = cols [128,256).
    const int half = wid & 1;
    const int c    = half * 128 + lane * 2;

    // Lane owns 2 columns; weights pre-scaled by RC*DT = 0.01. 64 VGPRs.
    f32x2 w[NINP];
#pragma unroll
    for (int k = 0; k < NINP; ++k) {
        f32x2 t = *reinterpret_cast<const f32x2*>(x2h + k * NHID + c);
        w[k] = t * 0.01f;
    }

    const int cw  = wid >> 1;                 // chunk-wave id (pair id)
    const int ncw = nwaves >> 1;              // number of pairs (4096)
    const int total_chunks = B / RPC;         // 65536
    const int nch = (total_chunks - cw + ncw - 1) / ncw;   // 16 exact at default launch
    if (nch <= 0) return;

    const float* src0 = x + (size_t)cw * (RPC * NINP) + lane * 4;
    const size_t src_stride = (size_t)ncw * (RPC * NINP);  // floats per chunk step

    stage_chunk(src0, &xbuf[wv][0][0]);
    if (nch > 1) stage_chunk(src0 + src_stride, &xbuf[wv][1][0]);

    for (int i = 0; i < nch; ++i) {
        // Counted waits (L=stage load, S=store). Iter body: [wait][16xS][L(i+2)].
        //   i==0: ops newer than L0 = {L1}                   -> vmcnt(1)
        //   mid:  ops newer than Li = {S(i-1) x16, L(i+1)}   -> vmcnt(17)
        //   last: ops newer than Ln = {S(n-1) x16}           -> vmcnt(16)
        if (i == 0) {
            if (nch > 1) asm volatile("s_waitcnt vmcnt(1)" ::: "memory");
            else         asm volatile("s_waitcnt vmcnt(0)" ::: "memory");
        } else if (i == nch - 1) {
            asm volatile("s_waitcnt vmcnt(16)" ::: "memory");
        } else {
            asm volatile("s_waitcnt vmcnt(17)" ::: "memory");
        }

        const float* xb = &xbuf[wv][i & 1][0];
        const size_t row0 = ((size_t)cw + (size_t)i * ncw) * RPC;

#pragma unroll 2
        for (int r = 0; r < RPC; ++r) {
            // uniform-address LDS reads -> free 16B broadcast to all lanes
            const f32x4* xr = (const f32x4*)(xb + r * NINP);
            f32x2 acc = {0.f, 0.f};
#pragma unroll
            for (int g = 0; g < 8; ++g) {
                f32x4 xq = xr[g];
                acc += w[4 * g + 0] * xq.x;
                acc += w[4 * g + 1] * xq.y;
                acc += w[4 * g + 2] * xq.z;
                acc += w[4 * g + 3] * xq.w;
            }
            const size_t base = (row0 + r) * NHID + c;
            __builtin_nontemporal_store(acc, (f32x2*)(u + base));
            f32x2 z = {0.f, 0.f};
            __builtin_nontemporal_store(z, (f32x2*)(spk + base));
        }

        if (i + 2 < nch) stage_chunk(src0 + (size_t)(i + 2) * src_stride, &xbuf[wv][i & 1][0]);
    }
}

extern "C" void kernel_launch(void* const* d_in, const int* in_sizes, int n_in,
                              void* d_out, int out_size, void* d_ws, size_t ws_size,
                              hipStream_t stream) {
    const float* x   = (const float*)d_in[0];
    const float* x2h = (const float*)d_in[1];
    // d_in[2] (h2h) is dead: recurrent input state is zero.

    const int B = in_sizes[0] / NINP;            // 524288
    float* u   = (float*)d_out;
    float* spk = u + (size_t)B * NHID;

    const int threads = 256;                     // 4 waves/block
    const int blocks  = 2048;                    // 8192 waves = 4096 pairs -> 16 chunks/pair
    const int nwaves  = blocks * (threads / 64); // exactly one resident generation
    lsm_kernel<<<blocks, threads, 0, stream>>>(x, x2h, u, spk, B, nwaves);
}

// Round 11
// 204.557 us; speedup vs baseline: 1.0155x; 1.0155x over previous
//
#include <hip/hip_runtime.h>
#include <stdint.h>

// u   = 0.01 * (x @ x2h)   [B=524288, K=32, N=256]
// spk = zeros              [B, 256]
// h2h is dead (recurrent state is zero for the single time step).
//
// FINAL: exact R4/R9 kernel (best measured: 204.8-205.0 us, 5.55 TB/s on
// 1.138 GB = 88% of the 6.29 TB/s mixed-stream copy ceiling).
// Frozen facts from this session:
//  - iteration body order [wait][compute+NT-store][prefetch] is mandatory:
//    any reorder (R7/R8) amplifies HBM traffic ~10x (write-combine breakage);
//  - nontemporal stores mandatory (write-allocate avoidance);
//  - 4 waves/SIMD occupancy (64 weight VGPRs, 2 cols/lane) beats 2 (+3%);
//  - fill-wave role split, producer/consumer decoupling, single-generation
//    grids all regress or are neutral.

#define NHID 256
#define NINP 32
#define RPC  8          // rows per chunk: 8*128B = 1 KB = one global_load_lds_dwordx4/wave

typedef float __attribute__((ext_vector_type(4))) f32x4;
typedef float __attribute__((ext_vector_type(2))) f32x2;

__device__ __forceinline__ void stage_chunk(const float* src_lane, void* lds_wave_base) {
    // global src is per-lane; LDS dst is wave-uniform base + lane*16 (HW rule).
    __builtin_amdgcn_global_load_lds(
        (const __attribute__((address_space(1))) uint32_t*)src_lane,
        (__attribute__((address_space(3))) uint32_t*)lds_wave_base,
        16, 0, 0);
}

__global__ __launch_bounds__(256, 4) void lsm_kernel(
    const float* __restrict__ x, const float* __restrict__ x2h,
    float* __restrict__ u, float* __restrict__ spk,
    int B, int nwaves)
{
    __shared__ float xbuf[4][2][RPC * NINP];   // 4 waves x double-buffer x 1 KB = 8 KB

    const int lane = threadIdx.x & 63;
    const int wv   = threadIdx.x >> 6;
    const int wid  = __builtin_amdgcn_readfirstlane(blockIdx.x * 4 + wv);

    // Wave pair: even wave = cols [0,128), odd wave = cols [128,256).
    const int half = wid & 1;
    const int c    = half * 128 + lane * 2;

    // Lane owns 2 columns; weights pre-scaled by RC*DT = 0.01. 64 VGPRs.
    f32x2 w[NINP];
#pragma unroll
    for (int k = 0; k < NINP; ++k) {
        f32x2 t = *reinterpret_cast<const f32x2*>(x2h + k * NHID + c);
        w[k] = t * 0.01f;
    }

    const int cw  = wid >> 1;                 // chunk-wave id (pair id)
    const int ncw = nwaves >> 1;              // number of pairs
    const int total_chunks = B / RPC;         // 65536
    const int nch = (total_chunks - cw + ncw - 1) / ncw;   // uniform (=8 at default launch)
    if (nch <= 0) return;

    const float* src0 = x + (size_t)cw * (RPC * NINP) + lane * 4;
    const size_t src_stride = (size_t)ncw * (RPC * NINP);  // floats per chunk step

    stage_chunk(src0, &xbuf[wv][0][0]);
    if (nch > 1) stage_chunk(src0 + src_stride, &xbuf[wv][1][0]);

    for (int i = 0; i < nch; ++i) {
        // Counted waits (L=stage load, S=store). Iter body: [wait][16xS][L(i+2)].
        //   i==0: ops newer than L0 = {L1}                   -> vmcnt(1)
        //   mid:  ops newer than Li = {S(i-1) x16, L(i+1)}   -> vmcnt(17)
        //   last: ops newer than Ln = {S(n-1) x16}           -> vmcnt(16)
        if (i == 0) {
            if (nch > 1) asm volatile("s_waitcnt vmcnt(1)" ::: "memory");
            else         asm volatile("s_waitcnt vmcnt(0)" ::: "memory");
        } else if (i == nch - 1) {
            asm volatile("s_waitcnt vmcnt(16)" ::: "memory");
        } else {
            asm volatile("s_waitcnt vmcnt(17)" ::: "memory");
        }

        const float* xb = &xbuf[wv][i & 1][0];
        const size_t row0 = ((size_t)cw + (size_t)i * ncw) * RPC;

#pragma unroll 2
        for (int r = 0; r < RPC; ++r) {
            // uniform-address LDS reads -> free 16B broadcast to all lanes
            const f32x4* xr = (const f32x4*)(xb + r * NINP);
            f32x2 acc = {0.f, 0.f};
#pragma unroll
            for (int g = 0; g < 8; ++g) {
                f32x4 xq = xr[g];
                acc += w[4 * g + 0] * xq.x;
                acc += w[4 * g + 1] * xq.y;
                acc += w[4 * g + 2] * xq.z;
                acc += w[4 * g + 3] * xq.w;
            }
            const size_t base = (row0 + r) * NHID + c;
            __builtin_nontemporal_store(acc, (f32x2*)(u + base));
            f32x2 z = {0.f, 0.f};
            __builtin_nontemporal_store(z, (f32x2*)(spk + base));
        }

        if (i + 2 < nch) stage_chunk(src0 + (size_t)(i + 2) * src_stride, &xbuf[wv][i & 1][0]);
    }
}

extern "C" void kernel_launch(void* const* d_in, const int* in_sizes, int n_in,
                              void* d_out, int out_size, void* d_ws, size_t ws_size,
                              hipStream_t stream) {
    const float* x   = (const float*)d_in[0];
    const float* x2h = (const float*)d_in[1];
    // d_in[2] (h2h) is dead: recurrent input state is zero.

    const int B = in_sizes[0] / NINP;            // 524288
    float* u   = (float*)d_out;
    float* spk = u + (size_t)B * NHID;

    const int threads = 256;                     // 4 waves/block
    const int blocks  = 4096;                    // 16384 waves = 8192 pairs -> 8 chunks/pair
    const int nwaves  = blocks * (threads / 64);
    lsm_kernel<<<blocks, threads, 0, stream>>>(x, x2h, u, spk, B, nwaves);
}